// Round 6
// baseline (424.074 us; speedup 1.0000x reference)
//
#include <hip/hip_runtime.h>
#include <math.h>

#define N_ROWS 16384
#define K_CODES 4096
#define D_DIM 512
#define NCHUNK 8
#define KCHUNK (K_CODES / NCHUNK)
#define N_TILES 32              // K_CODES / 128
#define MARGIN 2.5e-3f
#define ENTSLACK 1.0e-4f

typedef unsigned int uint32;
typedef unsigned short u16t;
typedef __attribute__((ext_vector_type(8))) short short8;
typedef __attribute__((ext_vector_type(4))) float f32x4;

__device__ __forceinline__ float fmul_(float a, float b) { return __fmul_rn(a, b); }
__device__ __forceinline__ float fadd_(float a, float b) { return __fadd_rn(a, b); }

__device__ __forceinline__ u16t f2bf(float x) {
    uint32 u = __float_as_uint(x);
    return (u16t)((u + 0x7fffu + ((u >> 16) & 1u)) >> 16);   // RNE
}
__device__ __forceinline__ float bf2f(u16t b) {
    return __uint_as_float(((uint32)b) << 16);
}

// ---------------------------------------------------------------- rownorm
// Bit-exact emulation of np.sum(x*x, axis=1), rows of 512 (verified R2-R5).
__global__ void rownorm_np_kernel(const float* __restrict__ src, int nrows,
                                  float* __restrict__ out) {
    int gid = blockIdx.x * blockDim.x + threadIdx.x;
    int row = gid >> 2;
    int blk = gid & 3;
    if (row >= nrows) return;
    const float4* p = (const float4*)(src + (size_t)row * D_DIM + blk * 128);
    float4 v0 = p[0], v1 = p[1];
    float r0 = fmul_(v0.x, v0.x), r1 = fmul_(v0.y, v0.y);
    float r2 = fmul_(v0.z, v0.z), r3 = fmul_(v0.w, v0.w);
    float r4 = fmul_(v1.x, v1.x), r5 = fmul_(v1.y, v1.y);
    float r6 = fmul_(v1.z, v1.z), r7 = fmul_(v1.w, v1.w);
#pragma unroll
    for (int i = 1; i < 16; i++) {
        float4 w0 = p[2 * i], w1 = p[2 * i + 1];
        r0 = fadd_(r0, fmul_(w0.x, w0.x));
        r1 = fadd_(r1, fmul_(w0.y, w0.y));
        r2 = fadd_(r2, fmul_(w0.z, w0.z));
        r3 = fadd_(r3, fmul_(w0.w, w0.w));
        r4 = fadd_(r4, fmul_(w1.x, w1.x));
        r5 = fadd_(r5, fmul_(w1.y, w1.y));
        r6 = fadd_(r6, fmul_(w1.z, w1.z));
        r7 = fadd_(r7, fmul_(w1.w, w1.w));
    }
    float s = fadd_(fadd_(fadd_(r0, r1), fadd_(r2, r3)),
                    fadd_(fadd_(r4, r5), fadd_(r6, r7)));
    float u = __shfl_down(s, 1, 64);
    float t = fadd_(s, u);
    float w = __shfl_down(t, 2, 64);
    float tot = fadd_(t, w);
    if (blk == 0) out[row] = tot;
}

// ---------------------------------------------------------------- cvt bf16 (verified R4)
__global__ void cvt_bf16_kernel(const float* __restrict__ src,
                                u16t* __restrict__ dst, int n4) {
    int i = blockIdx.x * blockDim.x + threadIdx.x;
    if (i >= n4) return;
    float4 v = ((const float4*)src)[i];
    ushort4 o;
    o.x = f2bf(v.x); o.y = f2bf(v.y); o.z = f2bf(v.z); o.w = f2bf(v.w);
    ((ushort4*)dst)[i] = o;
}

// ---------------------------------------------------------------- phase 1
// bf16 MFMA GEMM (BK=64) with fused per-tile candidate selection.
// Per 128x128 tile: exact per-row tile-min (shfl + LDS), emit candidates
// s <= tile_min + MARGIN into 4 slots/row, dump tmin/tcnt/tent tile-major.
__global__ __launch_bounds__(256) void score_cand_gemm_kernel(
    const u16t* __restrict__ zb, const u16t* __restrict__ cbb,
    const float* __restrict__ cnorm,
    float* __restrict__ tmin_g, uint32* __restrict__ tcnt_g,
    uint32* __restrict__ tent_g) {
    __shared__ alignas(16) u16t Ab[128 * 64];     // 16 KB
    __shared__ alignas(16) u16t Bb[128 * 64];     // 16 KB
    __shared__ float rmin2[2][128];
    __shared__ float tminS[128];
    __shared__ uint32 cntS[128];
    __shared__ alignas(16) uint32 entS[128][4];

    const int t = threadIdx.x;
    const int bx = blockIdx.x;            // k-chunk 0..7
    const int by = blockIdx.y;            // row tile 0..127
    const int row0 = by * 128, k0 = bx * KCHUNK;
    const int w = t >> 6, lane = t & 63;
    const int wx = w & 1, wy = w >> 1;
    const int l15 = lane & 15, quad = lane >> 4;
    const int srow8 = (lane >> 3);        // staging row sub-index
    const int scol = (lane & 7) * 8;      // staging col (elements)

    for (int kt = 0; kt < 4; kt++) {
        f32x4 acc[4][4];
#pragma unroll
        for (int i = 0; i < 4; i++)
#pragma unroll
            for (int j = 0; j < 4; j++) acc[i][j] = (f32x4){0.f, 0.f, 0.f, 0.f};

        for (int dt = 0; dt < 8; dt++) {
            __syncthreads();
#pragma unroll
            for (int q = 0; q < 4; q++) {
                int rin = q * 32 + w * 8 + srow8;
                const u16t* ga = zb + (size_t)(row0 + rin) * D_DIM + dt * 64 + scol;
                __builtin_amdgcn_global_load_lds(
                    (const __attribute__((address_space(1))) void*)ga,
                    (__attribute__((address_space(3))) void*)((char*)Ab + q * 4096 + w * 1024),
                    16, 0, 0);
                const u16t* gb = cbb + (size_t)(k0 + kt * 128 + rin) * D_DIM + dt * 64 + scol;
                __builtin_amdgcn_global_load_lds(
                    (const __attribute__((address_space(1))) void*)gb,
                    (__attribute__((address_space(3))) void*)((char*)Bb + q * 4096 + w * 1024),
                    16, 0, 0);
            }
            __syncthreads();
#pragma unroll
            for (int kk = 0; kk < 2; kk++) {
                short8 a[4], b[4];
#pragma unroll
                for (int i = 0; i < 4; i++)
                    a[i] = *(const short8*)((char*)Ab + (wy * 64 + i * 16 + l15) * 128 + kk * 64 + quad * 16);
#pragma unroll
                for (int j = 0; j < 4; j++)
                    b[j] = *(const short8*)((char*)Bb + (wx * 64 + j * 16 + l15) * 128 + kk * 64 + quad * 16);
#pragma unroll
                for (int i = 0; i < 4; i++)
#pragma unroll
                    for (int j = 0; j < 4; j++)
                        acc[i][j] = __builtin_amdgcn_mfma_f32_16x16x32_bf16(a[i], b[j], acc[i][j], 0, 0, 0);
            }
        }
        // ---------- epilogue: tile min + candidate emission ----------
        float cn[4];
#pragma unroll
        for (int j = 0; j < 4; j++)
            cn[j] = cnorm[k0 + kt * 128 + wx * 64 + j * 16 + l15];

        // per-thread per-row min over its 4 cols (rows: i*16+quad*4+r)
        float rm[16];
#pragma unroll
        for (int i = 0; i < 4; i++)
#pragma unroll
            for (int r = 0; r < 4; r++) {
                float m = 3.4e38f;
#pragma unroll
                for (int j = 0; j < 4; j++)
                    m = fminf(m, fmaf(-2.f, acc[i][j][r], cn[j]));
                rm[i * 4 + r] = m;
            }
        // reduce across the 16 l15 lanes sharing these rows (xor 1,2,4,8)
#pragma unroll
        for (int off = 1; off < 16; off <<= 1)
#pragma unroll
            for (int p = 0; p < 16; p++)
                rm[p] = fminf(rm[p], __shfl_xor(rm[p], off, 64));
        if (l15 == 0) {
#pragma unroll
            for (int p = 0; p < 16; p++)
                rmin2[wx][wy * 64 + (p >> 2) * 16 + quad * 4 + (p & 3)] = rm[p];
        }
        __syncthreads();
        if (t < 128) {
            tminS[t] = fminf(rmin2[0][t], rmin2[1][t]);
            cntS[t] = 0u;
        }
        __syncthreads();
        // emission: exact f32 s vs final tile_min + MARGIN
#pragma unroll
        for (int i = 0; i < 4; i++)
#pragma unroll
            for (int r = 0; r < 4; r++) {
                int rl = wy * 64 + i * 16 + quad * 4 + r;
                float thrR = tminS[rl] + MARGIN;
#pragma unroll
                for (int j = 0; j < 4; j++) {
                    float s = fmaf(-2.f, acc[i][j][r], cn[j]);
                    if (s <= thrR) {
                        uint32 pos = atomicAdd(&cntS[rl], 1u);
                        if (pos < 4u) {
                            uint32 klocal = (uint32)(wx * 64 + j * 16 + l15);
                            entS[rl][pos] = (klocal << 16) | (uint32)f2bf(s);
                        }
                    }
                }
            }
        __syncthreads();
        // dump tile-major (coalesced per block)
        if (t < 128) {
            int ti = bx * 4 + kt;
            size_t base = (size_t)ti * N_ROWS + row0 + t;
            tmin_g[base] = tminS[t];
            tcnt_g[base] = cntS[t];
            *(uint4*)&tent_g[base * 4] = *(const uint4*)&entS[t][0];
        }
        // next kt's first dt-barrier separates these LDS reads from reuse
    }
}

// ---------------------------------------------------------------- phase 2
// One WAVE per row: global min from 32 tile minima; skip tiles with
// tmin > gmin+MARGIN; exact np-fp32 refine of surviving candidates
// (dot/tie-break/STE code verbatim from verified R4/R5); fused epilogue.
__global__ __launch_bounds__(256) void refine2_kernel(
    const float* __restrict__ tmin_g, const uint32* __restrict__ tcnt_g,
    const uint32* __restrict__ tent_g,
    const float* __restrict__ z, const float* __restrict__ cb,
    const float* __restrict__ zz, const float* __restrict__ cnorm,
    float* __restrict__ out_zq, float* __restrict__ out_idx,
    float* __restrict__ rowsum) {
    const int t = threadIdx.x;
    const int w = t >> 6, lane = t & 63;
    const int row = blockIdx.x * 4 + w;

    // global coarse min over 32 tile minima
    float tml = (lane < N_TILES) ? tmin_g[(size_t)lane * N_ROWS + row] : 3.4e38f;
    float gm = tml;
#pragma unroll
    for (int off = 1; off < 64; off <<= 1)
        gm = fminf(gm, __shfl_xor(gm, off, 64));
    const float gthrA = gm + MARGIN;            // tile skip / superset bound
    const float gthrB = gthrA + ENTSLACK;       // bf16-stored-score test

    const float* zr = z + (size_t)row * D_DIM;
    float4 z0 = *(const float4*)(zr + lane * 8);
    float4 z1 = *(const float4*)(zr + lane * 8 + 4);
    const float zzr = zz[row];

    float bv = 3.4e38f;
    int bi = 0x7fffffff;

    auto refine = [&](int k) {
        const float* cr = cb + (size_t)k * D_DIM;
        float4 c0 = *(const float4*)(cr + lane * 8);
        float4 c1 = *(const float4*)(cr + lane * 8 + 4);
        float d = fmul_(z0.x, c0.x);
        d = fmaf(z0.y, c0.y, d); d = fmaf(z0.z, c0.z, d); d = fmaf(z0.w, c0.w, d);
        d = fmaf(z1.x, c1.x, d); d = fmaf(z1.y, c1.y, d);
        d = fmaf(z1.z, c1.z, d); d = fmaf(z1.w, c1.w, d);
#pragma unroll
        for (int off = 1; off < 64; off <<= 1)
            d = fadd_(d, __shfl_xor(d, off, 64));
        float dist = fmaf(-2.f, d, fadd_(zzr, cnorm[k]));
        // nondet candidate order -> full (value, index) tie-break
        if (dist < bv || (dist == bv && k < bi)) { bv = dist; bi = k; }
    };

    for (int ti = 0; ti < N_TILES; ti++) {
        float tmv = __shfl(tml, ti, 64);
        if (tmv > gthrA) continue;              // no candidate can qualify
        uint32 cnt = tcnt_g[(size_t)ti * N_ROWS + row];
        if (cnt <= 4u) {
            uint4 ev = *(const uint4*)&tent_g[((size_t)ti * N_ROWS + row) * 4];
            uint32 e4[4] = {ev.x, ev.y, ev.z, ev.w};
#pragma unroll
            for (uint32 e = 0; e < 4u; e++) {
                if (e < cnt) {
                    uint32 v = e4[e];
                    if (bf2f((u16t)(v & 0xffffu)) <= gthrB)
                        refine(ti * 128 + (int)(v >> 16));
                }
            }
        } else {
            // overflow (rare): exact rescan of the whole tile
            for (int kk = 0; kk < 128; kk++) refine(ti * 128 + kk);
        }
    }

    // bi is wave-uniform; fused STE write + rowsum (verbatim verified R5)
    const float* cq = cb + (size_t)bi * D_DIM;
    float4 c0 = *(const float4*)(cq + lane * 8);
    float4 c1 = *(const float4*)(cq + lane * 8 + 4);
    float4 o0, o1;
    o0.x = fadd_(z0.x, __fsub_rn(c0.x, z0.x));
    o0.y = fadd_(z0.y, __fsub_rn(c0.y, z0.y));
    o0.z = fadd_(z0.z, __fsub_rn(c0.z, z0.z));
    o0.w = fadd_(z0.w, __fsub_rn(c0.w, z0.w));
    o1.x = fadd_(z1.x, __fsub_rn(c1.x, z1.x));
    o1.y = fadd_(z1.y, __fsub_rn(c1.y, z1.y));
    o1.z = fadd_(z1.z, __fsub_rn(c1.z, z1.z));
    o1.w = fadd_(z1.w, __fsub_rn(c1.w, z1.w));
    float* orow = out_zq + (size_t)row * D_DIM + lane * 8;
    *(float4*)(orow) = o0;
    *(float4*)(orow + 4) = o1;
    float dx0 = z0.x - c0.x, dy0 = z0.y - c0.y, dz0 = z0.z - c0.z, dw0 = z0.w - c0.w;
    float dx1 = z1.x - c1.x, dy1 = z1.y - c1.y, dz1 = z1.z - c1.z, dw1 = z1.w - c1.w;
    float s = dx0 * dx0 + dy0 * dy0 + dz0 * dz0 + dw0 * dw0
            + dx1 * dx1 + dy1 * dy1 + dz1 * dz1 + dw1 * dw1;
#pragma unroll
    for (int off = 32; off; off >>= 1) s += __shfl_down(s, off, 64);
    if (lane == 0) {
        rowsum[row] = s;
        out_idx[row] = (float)bi;
    }
}

// ---------------------------------------------------------------- loss
__global__ void loss_kernel(const float* __restrict__ rowsum,
                            float* __restrict__ out_loss) {
    __shared__ float sm[256];
    float s = 0.f;
    for (int i = threadIdx.x; i < N_ROWS; i += 256) s += rowsum[i];
    sm[threadIdx.x] = s;
    __syncthreads();
    for (int st = 128; st; st >>= 1) {
        if (threadIdx.x < st) sm[threadIdx.x] += sm[threadIdx.x + st];
        __syncthreads();
    }
    if (threadIdx.x == 0)
        *out_loss = 1.25f * sm[0] / (float)(N_ROWS * D_DIM);
}

// ================================================================ fallback
// (verified round-2 fp32 path, used only if ws_size too small)
#define BM 128
#define BN 128
#define BK 16
#define TM 8
#define TN 8

__global__ __launch_bounds__(256, 4) void vq_argmin_kernel(
    const float* __restrict__ z, const float* __restrict__ cb,
    const float* __restrict__ zz, const float* __restrict__ cnorm,
    float* __restrict__ pval, int* __restrict__ pidx) {
    __shared__ float As[BK][BM + 4];
    __shared__ float Bs[BK][BN + 4];
    __shared__ float rv[BM][17];
    __shared__ int   ri[BM][17];

    const int bx = blockIdx.x;
    const int by = blockIdx.y;
    const int row0 = by * BM;
    const int k0 = bx * KCHUNK;
    const int t = threadIdx.x;
    const int tx = t & 15;
    const int ty = t >> 4;

    float minv[TM];
    int   mini[TM];
#pragma unroll
    for (int i = 0; i < TM; i++) { minv[i] = 3.4e38f; mini[i] = 0; }
    float zrow[TM];
#pragma unroll
    for (int i = 0; i < TM; i++) zrow[i] = zz[row0 + ty * TM + i];
    const int sr = t >> 1;
    const int sdq = (t & 1) * 8;

    for (int kt = 0; kt < KCHUNK / BN; kt++) {
        const int col0 = k0 + kt * BN;
        float acc[TM][TN];
#pragma unroll
        for (int i = 0; i < TM; i++)
#pragma unroll
            for (int j = 0; j < TN; j++) acc[i][j] = 0.f;
        for (int dt = 0; dt < D_DIM; dt += BK) {
            {
                const float* src = z + (size_t)(row0 + sr) * D_DIM + dt + sdq;
                float4 v0 = *(const float4*)(src);
                float4 v1 = *(const float4*)(src + 4);
                As[sdq + 0][sr] = v0.x; As[sdq + 1][sr] = v0.y;
                As[sdq + 2][sr] = v0.z; As[sdq + 3][sr] = v0.w;
                As[sdq + 4][sr] = v1.x; As[sdq + 5][sr] = v1.y;
                As[sdq + 6][sr] = v1.z; As[sdq + 7][sr] = v1.w;
                const float* srcb = cb + (size_t)(col0 + sr) * D_DIM + dt + sdq;
                float4 w0 = *(const float4*)(srcb);
                float4 w1 = *(const float4*)(srcb + 4);
                Bs[sdq + 0][sr] = w0.x; Bs[sdq + 1][sr] = w0.y;
                Bs[sdq + 2][sr] = w0.z; Bs[sdq + 3][sr] = w0.w;
                Bs[sdq + 4][sr] = w1.x; Bs[sdq + 5][sr] = w1.y;
                Bs[sdq + 6][sr] = w1.z; Bs[sdq + 7][sr] = w1.w;
            }
            __syncthreads();
#pragma unroll
            for (int d = 0; d < BK; d++) {
                float a[TM], b[TN];
#pragma unroll
                for (int i = 0; i < TM; i++) a[i] = As[d][ty * TM + i];
#pragma unroll
                for (int j = 0; j < TN; j++) b[j] = Bs[d][tx * TN + j];
#pragma unroll
                for (int i = 0; i < TM; i++)
#pragma unroll
                    for (int j = 0; j < TN; j++)
                        acc[i][j] = fmaf(a[i], b[j], acc[i][j]);
            }
            __syncthreads();
        }
#pragma unroll
        for (int j = 0; j < TN; j++) {
            const int col = col0 + tx * TN + j;
            const float cn = cnorm[col];
#pragma unroll
            for (int i = 0; i < TM; i++) {
                float s1 = fadd_(zrow[i], cn);
                float s = fmaf(-2.f, acc[i][j], s1);
                if (s < minv[i]) { minv[i] = s; mini[i] = col; }
            }
        }
    }
#pragma unroll
    for (int i = 0; i < TM; i++) {
        rv[ty * TM + i][tx] = minv[i];
        ri[ty * TM + i][tx] = mini[i];
    }
    __syncthreads();
    if (t < BM) {
        float bv = rv[t][0];
        int   bi = ri[t][0];
#pragma unroll
        for (int x = 1; x < 16; x++) {
            float v = rv[t][x]; int ii = ri[t][x];
            if (v < bv || (v == bv && ii < bi)) { bv = v; bi = ii; }
        }
        pval[(size_t)(row0 + t) * NCHUNK + bx] = bv;
        pidx[(size_t)(row0 + t) * NCHUNK + bx] = bi;
    }
}

__global__ void finalize_kernel(const float* __restrict__ z,
                                const float* __restrict__ cb,
                                const float* __restrict__ pval,
                                const int* __restrict__ pidx,
                                float* __restrict__ out_zq,
                                float* __restrict__ out_idx,
                                float* __restrict__ rowsum) {
    int row = (blockIdx.x * blockDim.x + threadIdx.x) >> 6;
    int lane = threadIdx.x & 63;
    if (row >= N_ROWS) return;
    float bv = pval[(size_t)row * NCHUNK];
    int   bi = pidx[(size_t)row * NCHUNK];
#pragma unroll
    for (int c = 1; c < NCHUNK; c++) {
        float v = pval[(size_t)row * NCHUNK + c];
        int  ii = pidx[(size_t)row * NCHUNK + c];
        if (v < bv || (v == bv && ii < bi)) { bv = v; bi = ii; }
    }
    const float4* zr = (const float4*)(z + (size_t)row * D_DIM);
    const float4* cr = (const float4*)(cb + (size_t)bi * D_DIM);
    float4* orow = (float4*)(out_zq + (size_t)row * D_DIM);
    float s = 0.f;
#pragma unroll
    for (int i = 0; i < 2; i++) {
        float4 zv = zr[i * 64 + lane];
        float4 cv = cr[i * 64 + lane];
        float4 o;
        o.x = fadd_(zv.x, __fsub_rn(cv.x, zv.x));
        o.y = fadd_(zv.y, __fsub_rn(cv.y, zv.y));
        o.z = fadd_(zv.z, __fsub_rn(cv.z, zv.z));
        o.w = fadd_(zv.w, __fsub_rn(cv.w, zv.w));
        orow[i * 64 + lane] = o;
        float dx = zv.x - cv.x, dy = zv.y - cv.y;
        float dz = zv.z - cv.z, dw = zv.w - cv.w;
        s += dx * dx + dy * dy + dz * dz + dw * dw;
    }
#pragma unroll
    for (int off = 32; off; off >>= 1) s += __shfl_down(s, off, 64);
    if (lane == 0) {
        rowsum[row] = s;
        out_idx[row] = (float)bi;
    }
}

// ---------------------------------------------------------------- launch
extern "C" void kernel_launch(void* const* d_in, const int* in_sizes, int n_in,
                              void* d_out, int out_size, void* d_ws, size_t ws_size,
                              hipStream_t stream) {
    const float* z  = (const float*)d_in[0];
    const float* cb = (const float*)d_in[1];
    float* out      = (float*)d_out;
    float* out_zq   = out;
    float* out_idx  = out + (size_t)N_ROWS * D_DIM;
    float* out_loss = out_idx + N_ROWS;

    float*  zz     = (float*)d_ws;                         // 16384 f32
    float*  cnorm  = zz + N_ROWS;                          // 4096 f32
    float*  rowsum = cnorm + K_CODES;                      // 16384 f32
    u16t*   z_bf   = (u16t*)(rowsum + N_ROWS);             // 16384*512 u16
    u16t*   cb_bf  = z_bf + (size_t)N_ROWS * D_DIM;        // 4096*512 u16
    float*  tmin_g = (float*)(cb_bf + (size_t)K_CODES * D_DIM);   // 32*16384 f32
    uint32* tcnt_g = (uint32*)(tmin_g + (size_t)N_TILES * N_ROWS);// 32*16384 u32
    uint32* tent_g = tcnt_g + (size_t)N_TILES * N_ROWS;    // 32*16384*4 u32
    const size_t WS_NEEDED = (size_t)(N_ROWS + K_CODES + N_ROWS) * 4
                           + (size_t)N_ROWS * D_DIM * 2
                           + (size_t)K_CODES * D_DIM * 2
                           + (size_t)N_TILES * N_ROWS * (4 + 4 + 16);

    if (ws_size >= WS_NEEDED) {
        cvt_bf16_kernel<<<(N_ROWS * D_DIM / 4) / 256, 256, 0, stream>>>(z, z_bf, N_ROWS * D_DIM / 4);
        cvt_bf16_kernel<<<(K_CODES * D_DIM / 4) / 256, 256, 0, stream>>>(cb, cb_bf, K_CODES * D_DIM / 4);
        rownorm_np_kernel<<<(N_ROWS * 4) / 256, 256, 0, stream>>>(z, N_ROWS, zz);
        rownorm_np_kernel<<<(K_CODES * 4) / 256, 256, 0, stream>>>(cb, K_CODES, cnorm);

        dim3 g1(NCHUNK, N_ROWS / 128);
        score_cand_gemm_kernel<<<g1, 256, 0, stream>>>(z_bf, cb_bf, cnorm,
                                                       tmin_g, tcnt_g, tent_g);
        refine2_kernel<<<N_ROWS / 4, 256, 0, stream>>>(tmin_g, tcnt_g, tent_g,
                                                       z, cb, zz, cnorm,
                                                       out_zq, out_idx, rowsum);
        loss_kernel<<<1, 256, 0, stream>>>(rowsum, out_loss);
    } else {
        // fallback: verified round-2 fp32 path (~1 MB ws)
        float* pval = rowsum + N_ROWS;
        int*   pidx = (int*)(pval + (size_t)N_ROWS * NCHUNK);
        rownorm_np_kernel<<<(N_ROWS * 4) / 256, 256, 0, stream>>>(z, N_ROWS, zz);
        rownorm_np_kernel<<<(K_CODES * 4) / 256, 256, 0, stream>>>(cb, K_CODES, cnorm);
        dim3 g2(NCHUNK, N_ROWS / BM);
        vq_argmin_kernel<<<g2, 256, 0, stream>>>(z, cb, zz, cnorm, pval, pidx);
        finalize_kernel<<<N_ROWS / 4, 256, 0, stream>>>(z, cb, pval, pidx,
                                                        out_zq, out_idx, rowsum);
        loss_kernel<<<1, 256, 0, stream>>>(rowsum, out_loss);
    }
}

// Round 7
// 291.449 us; speedup vs baseline: 1.4551x; 1.4551x over previous
//
#include <hip/hip_runtime.h>
#include <math.h>

#define N_ROWS 16384
#define K_CODES 4096
#define D_DIM 512
#define NCHUNK 8
#define KCHUNK (K_CODES / NCHUNK)
#define MARGIN 2.5e-3f

typedef unsigned int uint32;
typedef unsigned short u16t;
typedef __attribute__((ext_vector_type(8))) short short8;
typedef __attribute__((ext_vector_type(4))) float f32x4;

__device__ __forceinline__ float fmul_(float a, float b) { return __fmul_rn(a, b); }
__device__ __forceinline__ float fadd_(float a, float b) { return __fadd_rn(a, b); }

__device__ __forceinline__ u16t f2bf(float x) {
    uint32 u = __float_as_uint(x);
    return (u16t)((u + 0x7fffu + ((u >> 16) & 1u)) >> 16);   // RNE
}
__device__ __forceinline__ float bf2f(u16t b) {
    return __uint_as_float(((uint32)b) << 16);
}

// ---------------------------------------------------------------- rownorm
// Bit-exact emulation of np.sum(x*x, axis=1), rows of 512 (verified R2-R6).
__global__ void rownorm_np_kernel(const float* __restrict__ src, int nrows,
                                  float* __restrict__ out) {
    int gid = blockIdx.x * blockDim.x + threadIdx.x;
    int row = gid >> 2;
    int blk = gid & 3;
    if (row >= nrows) return;
    const float4* p = (const float4*)(src + (size_t)row * D_DIM + blk * 128);
    float4 v0 = p[0], v1 = p[1];
    float r0 = fmul_(v0.x, v0.x), r1 = fmul_(v0.y, v0.y);
    float r2 = fmul_(v0.z, v0.z), r3 = fmul_(v0.w, v0.w);
    float r4 = fmul_(v1.x, v1.x), r5 = fmul_(v1.y, v1.y);
    float r6 = fmul_(v1.z, v1.z), r7 = fmul_(v1.w, v1.w);
#pragma unroll
    for (int i = 1; i < 16; i++) {
        float4 w0 = p[2 * i], w1 = p[2 * i + 1];
        r0 = fadd_(r0, fmul_(w0.x, w0.x));
        r1 = fadd_(r1, fmul_(w0.y, w0.y));
        r2 = fadd_(r2, fmul_(w0.z, w0.z));
        r3 = fadd_(r3, fmul_(w0.w, w0.w));
        r4 = fadd_(r4, fmul_(w1.x, w1.x));
        r5 = fadd_(r5, fmul_(w1.y, w1.y));
        r6 = fadd_(r6, fmul_(w1.z, w1.z));
        r7 = fadd_(r7, fmul_(w1.w, w1.w));
    }
    float s = fadd_(fadd_(fadd_(r0, r1), fadd_(r2, r3)),
                    fadd_(fadd_(r4, r5), fadd_(r6, r7)));
    float u = __shfl_down(s, 1, 64);
    float t = fadd_(s, u);
    float w = __shfl_down(t, 2, 64);
    float tot = fadd_(t, w);
    if (blk == 0) out[row] = tot;
}

// ---------------------------------------------------------------- cvt bf16 (verified R4)
__global__ void cvt_bf16_kernel(const float* __restrict__ src,
                                u16t* __restrict__ dst, int n4) {
    int i = blockIdx.x * blockDim.x + threadIdx.x;
    if (i >= n4) return;
    float4 v = ((const float4*)src)[i];
    ushort4 o;
    o.x = f2bf(v.x); o.y = f2bf(v.y); o.z = f2bf(v.z); o.w = f2bf(v.w);
    ((ushort4*)dst)[i] = o;
}

// ---------------------------------------------------------------- phase 1
// bf16 MFMA GEMM; epilogue writes coarse scores s = cc - 2*z.c as bf16 to
// global via padded LDS tile (VERBATIM from R4: measured 137 us, absmax 0).
#define STS 136   // stile stride in u16 (272 B, keeps b128 alignment)

__global__ __launch_bounds__(256) void score_gemm_kernel(
    const u16t* __restrict__ zb, const u16t* __restrict__ cbb,
    const float* __restrict__ cnorm, u16t* __restrict__ scores) {
    __shared__ alignas(16) u16t Ab[128 * 32];
    __shared__ alignas(16) u16t Bb[128 * 32];
    __shared__ alignas(16) u16t stile[128 * STS];

    const int t = threadIdx.x;
    const int bx = blockIdx.x;
    const int by = blockIdx.y;
    const int row0 = by * 128, k0 = bx * KCHUNK;
    const int w = t >> 6, lane = t & 63;
    const int wx = w & 1, wy = w >> 1;
    const int l15 = lane & 15, quad = lane >> 4;

    for (int kt = 0; kt < 4; kt++) {
        f32x4 acc[4][4];
#pragma unroll
        for (int i = 0; i < 4; i++)
#pragma unroll
            for (int j = 0; j < 4; j++) acc[i][j] = (f32x4){0.f, 0.f, 0.f, 0.f};

        for (int dt = 0; dt < 16; dt++) {
            __syncthreads();
#pragma unroll
            for (int q = 0; q < 2; q++) {
                int s = q * 256 + t;
                const u16t* ga = zb + (size_t)(row0 + (s >> 2)) * D_DIM + dt * 32 + (s & 3) * 8;
                __builtin_amdgcn_global_load_lds(
                    (const __attribute__((address_space(1))) void*)ga,
                    (__attribute__((address_space(3))) void*)((char*)Ab + q * 4096 + w * 1024),
                    16, 0, 0);
                const u16t* gb = cbb + (size_t)(k0 + kt * 128 + (s >> 2)) * D_DIM + dt * 32 + (s & 3) * 8;
                __builtin_amdgcn_global_load_lds(
                    (const __attribute__((address_space(1))) void*)gb,
                    (__attribute__((address_space(3))) void*)((char*)Bb + q * 4096 + w * 1024),
                    16, 0, 0);
            }
            __syncthreads();
            short8 a[4], b[4];
#pragma unroll
            for (int i = 0; i < 4; i++)
                a[i] = *(const short8*)((char*)Ab + (wy * 64 + i * 16 + l15) * 64 + quad * 16);
#pragma unroll
            for (int j = 0; j < 4; j++)
                b[j] = *(const short8*)((char*)Bb + (wx * 64 + j * 16 + l15) * 64 + quad * 16);
#pragma unroll
            for (int i = 0; i < 4; i++)
#pragma unroll
                for (int j = 0; j < 4; j++)
                    acc[i][j] = __builtin_amdgcn_mfma_f32_16x16x32_bf16(a[i], b[j], acc[i][j], 0, 0, 0);
        }
        // pack scores to LDS tile (row-major, padded stride)
#pragma unroll
        for (int j = 0; j < 4; j++) {
            int cl = wx * 64 + j * 16 + l15;
            float cn = cnorm[k0 + kt * 128 + cl];
#pragma unroll
            for (int i = 0; i < 4; i++) {
#pragma unroll
                for (int r = 0; r < 4; r++) {
                    int rl = wy * 64 + i * 16 + quad * 4 + r;
                    float s = fmaf(-2.f, acc[i][j][r], cn);
                    stile[rl * STS + cl] = f2bf(s);
                }
            }
        }
        __syncthreads();
        // coalesced store: 128 rows x 128 u16
        for (int idx = t; idx < 128 * 16; idx += 256) {
            int row = idx >> 4, seg = idx & 15;
            short8 v = *(const short8*)&stile[row * STS + seg * 8];
            *(short8*)(scores + (size_t)(row0 + row) * K_CODES + k0 + kt * 128 + seg * 8) = v;
        }
        // next kt's first __syncthreads (dt loop head) protects stile reuse
    }
}

// ---------------------------------------------------------------- phase 2
// One WAVE per row, zero LDS, zero barriers (VERBATIM logic from R5, which
// passed absmax=0). Min via shfl butterfly; candidates ascending-k via
// ballot; exact np-fp32 dist + first-occurrence tie-break; fused epilogue.
__global__ __launch_bounds__(256) void scan_refine_wave_kernel(
    const u16t* __restrict__ scores,
    const float* __restrict__ z, const float* __restrict__ cb,
    const float* __restrict__ zz, const float* __restrict__ cnorm,
    float* __restrict__ out_zq, float* __restrict__ out_idx,
    float* __restrict__ rowsum) {
    const int t = threadIdx.x;
    const int w = t >> 6, lane = t & 63;
    const int row = blockIdx.x * 4 + w;

    // load this row's 4096 bf16 scores: 8 x b128 per lane (64 scores)
    const u16t* srow = scores + (size_t)row * K_CODES;
    short8 sv[8];
#pragma unroll
    for (int p = 0; p < 8; p++)
        sv[p] = *(const short8*)(srow + p * 512 + lane * 8);

    float m = 3.4e38f;
#pragma unroll
    for (int p = 0; p < 8; p++)
#pragma unroll
        for (int e = 0; e < 8; e++)
            m = fminf(m, bf2f((u16t)sv[p][e]));
#pragma unroll
    for (int off = 1; off < 64; off <<= 1)
        m = fminf(m, __shfl_xor(m, off, 64));
    const float thr = m + MARGIN;

    const float* zr = z + (size_t)row * D_DIM;
    float4 z0 = *(const float4*)(zr + lane * 8);
    float4 z1 = *(const float4*)(zr + lane * 8 + 4);
    const float zzr = zz[row];

    float bv = 3.4e38f;
    int bi = 0x7fffffff;
#pragma unroll
    for (int p = 0; p < 8; p++) {
        uint32 lm = 0u;
#pragma unroll
        for (int e = 0; e < 8; e++)
            if (bf2f((u16t)sv[p][e]) <= thr) lm |= (1u << e);
        unsigned long long act = __ballot(lm != 0u);
        while (act) {
            int src = __ffsll(act) - 1;
            act &= act - 1;
            uint32 mb = (uint32)__shfl((int)lm, src, 64);
            while (mb) {
                int e = __ffs(mb) - 1;
                mb &= mb - 1;
                int k = p * 512 + src * 8 + e;
                const float* cr = cb + (size_t)k * D_DIM;
                float4 c0 = *(const float4*)(cr + lane * 8);
                float4 c1 = *(const float4*)(cr + lane * 8 + 4);
                float d = fmul_(z0.x, c0.x);
                d = fmaf(z0.y, c0.y, d); d = fmaf(z0.z, c0.z, d); d = fmaf(z0.w, c0.w, d);
                d = fmaf(z1.x, c1.x, d); d = fmaf(z1.y, c1.y, d);
                d = fmaf(z1.z, c1.z, d); d = fmaf(z1.w, c1.w, d);
#pragma unroll
                for (int off = 1; off < 64; off <<= 1)
                    d = fadd_(d, __shfl_xor(d, off, 64));
                float dist = fmaf(-2.f, d, fadd_(zzr, cnorm[k]));
                // ascending k + strict < = first occurrence; tie-guard kept
                if (dist < bv || (dist == bv && k < bi)) { bv = dist; bi = k; }
            }
        }
    }
    // bi is wave-uniform (all lanes computed identical dist sequence)
    const float* cq = cb + (size_t)bi * D_DIM;
    float4 c0 = *(const float4*)(cq + lane * 8);
    float4 c1 = *(const float4*)(cq + lane * 8 + 4);
    float4 o0, o1;
    o0.x = fadd_(z0.x, __fsub_rn(c0.x, z0.x));
    o0.y = fadd_(z0.y, __fsub_rn(c0.y, z0.y));
    o0.z = fadd_(z0.z, __fsub_rn(c0.z, z0.z));
    o0.w = fadd_(z0.w, __fsub_rn(c0.w, z0.w));
    o1.x = fadd_(z1.x, __fsub_rn(c1.x, z1.x));
    o1.y = fadd_(z1.y, __fsub_rn(c1.y, z1.y));
    o1.z = fadd_(z1.z, __fsub_rn(c1.z, z1.z));
    o1.w = fadd_(z1.w, __fsub_rn(c1.w, z1.w));
    float* orow = out_zq + (size_t)row * D_DIM + lane * 8;
    *(float4*)(orow) = o0;
    *(float4*)(orow + 4) = o1;
    float dx0 = z0.x - c0.x, dy0 = z0.y - c0.y, dz0 = z0.z - c0.z, dw0 = z0.w - c0.w;
    float dx1 = z1.x - c1.x, dy1 = z1.y - c1.y, dz1 = z1.z - c1.z, dw1 = z1.w - c1.w;
    float s = dx0 * dx0 + dy0 * dy0 + dz0 * dz0 + dw0 * dw0
            + dx1 * dx1 + dy1 * dy1 + dz1 * dz1 + dw1 * dw1;
#pragma unroll
    for (int off = 32; off; off >>= 1) s += __shfl_down(s, off, 64);
    if (lane == 0) {
        rowsum[row] = s;
        out_idx[row] = (float)bi;
    }
}

// ---------------------------------------------------------------- loss
__global__ void loss_kernel(const float* __restrict__ rowsum,
                            float* __restrict__ out_loss) {
    __shared__ float sm[256];
    float s = 0.f;
    for (int i = threadIdx.x; i < N_ROWS; i += 256) s += rowsum[i];
    sm[threadIdx.x] = s;
    __syncthreads();
    for (int st = 128; st; st >>= 1) {
        if (threadIdx.x < st) sm[threadIdx.x] += sm[threadIdx.x + st];
        __syncthreads();
    }
    if (threadIdx.x == 0)
        *out_loss = 1.25f * sm[0] / (float)(N_ROWS * D_DIM);
}

// ================================================================ fallback
// (verified round-2 fp32 path, used only if ws_size too small)
#define BM 128
#define BN 128
#define BK 16
#define TM 8
#define TN 8

__global__ __launch_bounds__(256, 4) void vq_argmin_kernel(
    const float* __restrict__ z, const float* __restrict__ cb,
    const float* __restrict__ zz, const float* __restrict__ cnorm,
    float* __restrict__ pval, int* __restrict__ pidx) {
    __shared__ float As[BK][BM + 4];
    __shared__ float Bs[BK][BN + 4];
    __shared__ float rv[BM][17];
    __shared__ int   ri[BM][17];

    const int bx = blockIdx.x;
    const int by = blockIdx.y;
    const int row0 = by * BM;
    const int k0 = bx * KCHUNK;
    const int t = threadIdx.x;
    const int tx = t & 15;
    const int ty = t >> 4;

    float minv[TM];
    int   mini[TM];
#pragma unroll
    for (int i = 0; i < TM; i++) { minv[i] = 3.4e38f; mini[i] = 0; }
    float zrow[TM];
#pragma unroll
    for (int i = 0; i < TM; i++) zrow[i] = zz[row0 + ty * TM + i];
    const int sr = t >> 1;
    const int sdq = (t & 1) * 8;

    for (int kt = 0; kt < KCHUNK / BN; kt++) {
        const int col0 = k0 + kt * BN;
        float acc[TM][TN];
#pragma unroll
        for (int i = 0; i < TM; i++)
#pragma unroll
            for (int j = 0; j < TN; j++) acc[i][j] = 0.f;
        for (int dt = 0; dt < D_DIM; dt += BK) {
            {
                const float* src = z + (size_t)(row0 + sr) * D_DIM + dt + sdq;
                float4 v0 = *(const float4*)(src);
                float4 v1 = *(const float4*)(src + 4);
                As[sdq + 0][sr] = v0.x; As[sdq + 1][sr] = v0.y;
                As[sdq + 2][sr] = v0.z; As[sdq + 3][sr] = v0.w;
                As[sdq + 4][sr] = v1.x; As[sdq + 5][sr] = v1.y;
                As[sdq + 6][sr] = v1.z; As[sdq + 7][sr] = v1.w;
                const float* srcb = cb + (size_t)(col0 + sr) * D_DIM + dt + sdq;
                float4 w0 = *(const float4*)(srcb);
                float4 w1 = *(const float4*)(srcb + 4);
                Bs[sdq + 0][sr] = w0.x; Bs[sdq + 1][sr] = w0.y;
                Bs[sdq + 2][sr] = w0.z; Bs[sdq + 3][sr] = w0.w;
                Bs[sdq + 4][sr] = w1.x; Bs[sdq + 5][sr] = w1.y;
                Bs[sdq + 6][sr] = w1.z; Bs[sdq + 7][sr] = w1.w;
            }
            __syncthreads();
#pragma unroll
            for (int d = 0; d < BK; d++) {
                float a[TM], b[TN];
#pragma unroll
                for (int i = 0; i < TM; i++) a[i] = As[d][ty * TM + i];
#pragma unroll
                for (int j = 0; j < TN; j++) b[j] = Bs[d][tx * TN + j];
#pragma unroll
                for (int i = 0; i < TM; i++)
#pragma unroll
                    for (int j = 0; j < TN; j++)
                        acc[i][j] = fmaf(a[i], b[j], acc[i][j]);
            }
            __syncthreads();
        }
#pragma unroll
        for (int j = 0; j < TN; j++) {
            const int col = col0 + tx * TN + j;
            const float cn = cnorm[col];
#pragma unroll
            for (int i = 0; i < TM; i++) {
                float s1 = fadd_(zrow[i], cn);
                float s = fmaf(-2.f, acc[i][j], s1);
                if (s < minv[i]) { minv[i] = s; mini[i] = col; }
            }
        }
    }
#pragma unroll
    for (int i = 0; i < TM; i++) {
        rv[ty * TM + i][tx] = minv[i];
        ri[ty * TM + i][tx] = mini[i];
    }
    __syncthreads();
    if (t < BM) {
        float bv = rv[t][0];
        int   bi = ri[t][0];
#pragma unroll
        for (int x = 1; x < 16; x++) {
            float v = rv[t][x]; int ii = ri[t][x];
            if (v < bv || (v == bv && ii < bi)) { bv = v; bi = ii; }
        }
        pval[(size_t)(row0 + t) * NCHUNK + bx] = bv;
        pidx[(size_t)(row0 + t) * NCHUNK + bx] = bi;
    }
}

__global__ void finalize_kernel(const float* __restrict__ z,
                                const float* __restrict__ cb,
                                const float* __restrict__ pval,
                                const int* __restrict__ pidx,
                                float* __restrict__ out_zq,
                                float* __restrict__ out_idx,
                                float* __restrict__ rowsum) {
    int row = (blockIdx.x * blockDim.x + threadIdx.x) >> 6;
    int lane = threadIdx.x & 63;
    if (row >= N_ROWS) return;
    float bv = pval[(size_t)row * NCHUNK];
    int   bi = pidx[(size_t)row * NCHUNK];
#pragma unroll
    for (int c = 1; c < NCHUNK; c++) {
        float v = pval[(size_t)row * NCHUNK + c];
        int  ii = pidx[(size_t)row * NCHUNK + c];
        if (v < bv || (v == bv && ii < bi)) { bv = v; bi = ii; }
    }
    const float4* zr = (const float4*)(z + (size_t)row * D_DIM);
    const float4* cr = (const float4*)(cb + (size_t)bi * D_DIM);
    float4* orow = (float4*)(out_zq + (size_t)row * D_DIM);
    float s = 0.f;
#pragma unroll
    for (int i = 0; i < 2; i++) {
        float4 zv = zr[i * 64 + lane];
        float4 cv = cr[i * 64 + lane];
        float4 o;
        o.x = fadd_(zv.x, __fsub_rn(cv.x, zv.x));
        o.y = fadd_(zv.y, __fsub_rn(cv.y, zv.y));
        o.z = fadd_(zv.z, __fsub_rn(cv.z, zv.z));
        o.w = fadd_(zv.w, __fsub_rn(cv.w, zv.w));
        orow[i * 64 + lane] = o;
        float dx = zv.x - cv.x, dy = zv.y - cv.y;
        float dz = zv.z - cv.z, dw = zv.w - cv.w;
        s += dx * dx + dy * dy + dz * dz + dw * dw;
    }
#pragma unroll
    for (int off = 32; off; off >>= 1) s += __shfl_down(s, off, 64);
    if (lane == 0) {
        rowsum[row] = s;
        out_idx[row] = (float)bi;
    }
}

// ---------------------------------------------------------------- launch
extern "C" void kernel_launch(void* const* d_in, const int* in_sizes, int n_in,
                              void* d_out, int out_size, void* d_ws, size_t ws_size,
                              hipStream_t stream) {
    const float* z  = (const float*)d_in[0];
    const float* cb = (const float*)d_in[1];
    float* out      = (float*)d_out;
    float* out_zq   = out;
    float* out_idx  = out + (size_t)N_ROWS * D_DIM;
    float* out_loss = out_idx + N_ROWS;

    float* zz     = (float*)d_ws;                          // 16384 f32
    float* cnorm  = zz + N_ROWS;                           // 4096 f32
    float* rowsum = cnorm + K_CODES;                       // 16384 f32
    u16t*  z_bf   = (u16t*)(rowsum + N_ROWS);              // 16384*512 u16
    u16t*  cb_bf  = z_bf + (size_t)N_ROWS * D_DIM;         // 4096*512 u16
    u16t*  scores = cb_bf + (size_t)K_CODES * D_DIM;       // 16384*4096 u16
    const size_t WS_NEEDED = (size_t)(N_ROWS + K_CODES + N_ROWS) * 4
                           + (size_t)N_ROWS * D_DIM * 2
                           + (size_t)K_CODES * D_DIM * 2
                           + (size_t)N_ROWS * K_CODES * 2;

    if (ws_size >= WS_NEEDED) {
        cvt_bf16_kernel<<<(N_ROWS * D_DIM / 4) / 256, 256, 0, stream>>>(z, z_bf, N_ROWS * D_DIM / 4);
        cvt_bf16_kernel<<<(K_CODES * D_DIM / 4) / 256, 256, 0, stream>>>(cb, cb_bf, K_CODES * D_DIM / 4);
        rownorm_np_kernel<<<(N_ROWS * 4) / 256, 256, 0, stream>>>(z, N_ROWS, zz);
        rownorm_np_kernel<<<(K_CODES * 4) / 256, 256, 0, stream>>>(cb, K_CODES, cnorm);

        dim3 g1(NCHUNK, N_ROWS / 128);
        score_gemm_kernel<<<g1, 256, 0, stream>>>(z_bf, cb_bf, cnorm, scores);
        scan_refine_wave_kernel<<<N_ROWS / 4, 256, 0, stream>>>(scores, z, cb, zz, cnorm,
                                                                out_zq, out_idx, rowsum);
        loss_kernel<<<1, 256, 0, stream>>>(rowsum, out_loss);
    } else {
        // fallback: verified round-2 fp32 path (~1 MB ws)
        float* pval = rowsum + N_ROWS;
        int*   pidx = (int*)(pval + (size_t)N_ROWS * NCHUNK);
        rownorm_np_kernel<<<(N_ROWS * 4) / 256, 256, 0, stream>>>(z, N_ROWS, zz);
        rownorm_np_kernel<<<(K_CODES * 4) / 256, 256, 0, stream>>>(cb, K_CODES, cnorm);
        dim3 g2(NCHUNK, N_ROWS / BM);
        vq_argmin_kernel<<<g2, 256, 0, stream>>>(z, cb, zz, cnorm, pval, pidx);
        finalize_kernel<<<N_ROWS / 4, 256, 0, stream>>>(z, cb, pval, pidx,
                                                        out_zq, out_idx, rowsum);
        loss_kernel<<<1, 256, 0, stream>>>(rowsum, out_loss);
    }
}